// Round 2
// baseline (2499.176 us; speedup 1.0000x reference)
//
#include <hip/hip_runtime.h>
#include <stdint.h>
#include <stddef.h>

// ---------------------------------------------------------------------------
// FedLite quantize: 8 independent KMeans (N=4096, d=1024, L=64, 10 iters)
// pts = x viewed as [R=8][N=4096][SUBD=1024] (reshape is layout-preserving).
// Init indices reproduce jax.random (threefry2x32, partitionable mode).
//
// Round-2 structure:
//   k_rng (1024 thr, split u32 key/payload bitonic)      ~30us
//   k_x2, k_gather_init                                  small
//   10x [ k_assign -> k_sort (stable counting sort of labels)
//         -> k_centers (per-(r,l) gather-sum, no LDS accumulator) ]
//   final k_assign writes d_out directly (gather fused)
// ---------------------------------------------------------------------------

static constexpr int R_    = 8;
static constexpr int N_    = 4096;
static constexpr int L_    = 64;
static constexpr int D_    = 1024;   // SUBD
static constexpr int ITERS = 10;
static constexpr int ROWS  = R_ * N_;   // 32768 total sub-vectors

// ---------------------------------------------------------------------------
// Threefry2x32 (JAX flavor): 20 rounds, rotations {13,15,26,6}/{17,29,16,24}
// ---------------------------------------------------------------------------
__device__ __forceinline__ unsigned rotl32(unsigned x, int r) {
  return (x << r) | (x >> (32 - r));
}

__device__ __forceinline__ void tf2x32(unsigned k0, unsigned k1,
                                       unsigned c0, unsigned c1,
                                       unsigned &o0, unsigned &o1) {
  unsigned ks2 = k0 ^ k1 ^ 0x1BD11BDAu;
  unsigned x0 = c0 + k0, x1 = c1 + k1;
#define TF_R4(a,b,c,d) { x0 += x1; x1 = rotl32(x1,a); x1 ^= x0; \
                         x0 += x1; x1 = rotl32(x1,b); x1 ^= x0; \
                         x0 += x1; x1 = rotl32(x1,c); x1 ^= x0; \
                         x0 += x1; x1 = rotl32(x1,d); x1 ^= x0; }
  TF_R4(13,15,26,6);  x0 += k1;  x1 += ks2 + 1u;
  TF_R4(17,29,16,24); x0 += ks2; x1 += k0  + 2u;
  TF_R4(13,15,26,6);  x0 += k0;  x1 += k1  + 3u;
  TF_R4(17,29,16,24); x0 += k1;  x1 += ks2 + 4u;
  TF_R4(13,15,26,6);  x0 += ks2; x1 += k0  + 5u;
#undef TF_R4
  o0 = x0; o1 = x1;
}

// split(key) -> (new_key, subkey), partitionable mode (verified round 1)
__device__ __forceinline__ void jax_split2(unsigned k0, unsigned k1,
                                           unsigned &nk0, unsigned &nk1,
                                           unsigned &sk0, unsigned &sk1) {
  tf2x32(k0, k1, 0u, 0u, nk0, nk1);
  tf2x32(k0, k1, 0u, 1u, sk0, sk1);
}

// ---------------------------------------------------------------------------
// RNG kernel: one block (1024 thr) per KMeans problem r.
// init_idx[r][0..63] = jax.random.permutation(key_r, 4096)[:64] via 2 rounds
// of stable sort by threefry keys. Stable sort == bitonic on lexicographic
// (key32, slot12|value12) with unique slot.  Split u32 arrays to avoid the
// u64 LDS conflict pattern (round-1: 244k conflicts, 154us).
// ---------------------------------------------------------------------------
__global__ __launch_bounds__(1024) void k_rng(int* __restrict__ init_idx) {
  __shared__ unsigned skey[N_];
  __shared__ unsigned spay[N_];
  __shared__ unsigned short perm[N_];
  const int r = blockIdx.x;
  const int t = threadIdx.x;

  unsigned k0, k1;
  tf2x32(0u, 42u, 0u, (unsigned)r, k0, k1);   // key_r = split(key(42), 8)[r]

  for (int i = t; i < N_; i += 1024) perm[i] = (unsigned short)i;
  __syncthreads();

  for (int round = 0; round < 2; ++round) {
    unsigned nk0, nk1, s0, s1;
    jax_split2(k0, k1, nk0, nk1, s0, s1);
    for (int j = t; j < N_; j += 1024) {
      unsigned o0, o1;
      tf2x32(s0, s1, 0u, (unsigned)j, o0, o1);
      skey[j] = o0 ^ o1;                                   // random_bits(32)
      spay[j] = ((unsigned)j << 12) | (unsigned)perm[j];   // slot|value
    }
    __syncthreads();
    for (int k = 2; k <= N_; k <<= 1) {
      for (int j2 = k >> 1; j2 >= 1; j2 >>= 1) {
        for (int q = t; q < N_ / 2; q += 1024) {
          int low = q & (j2 - 1);
          int i0 = ((q ^ low) << 1) | low;
          int i1 = i0 | j2;
          bool up = ((i0 & k) == 0);
          unsigned ka = skey[i0], kb = skey[i1];
          unsigned pa = spay[i0], pb = spay[i1];
          bool agtb = (ka > kb) || (ka == kb && pa > pb);
          if (agtb == up) {
            skey[i0] = kb; skey[i1] = ka;
            spay[i0] = pb; spay[i1] = pa;
          }
        }
        __syncthreads();
      }
    }
    for (int j = t; j < N_; j += 1024) perm[j] = (unsigned short)(spay[j] & 0xFFFu);
    __syncthreads();
    k0 = nk0; k1 = nk1;
  }
  if (t < L_) init_idx[r * L_ + t] = (int)perm[t];
}

// ---------------------------------------------------------------------------
// x2[row] = sum of squares of pts row (computed once). 4 rows per block.
// ---------------------------------------------------------------------------
__global__ __launch_bounds__(256) void k_x2(const float* __restrict__ pts,
                                            float* __restrict__ x2) {
  const int t = threadIdx.x;
  const int lane = t & 63;
  const int row = blockIdx.x * 4 + (t >> 6);
  const float4* P = (const float4*)(pts + (size_t)row * D_);
  float s = 0.f;
#pragma unroll
  for (int i = 0; i < 4; ++i) {
    float4 v = P[lane + 64 * i];
    s += v.x * v.x + v.y * v.y + v.z * v.z + v.w * v.w;
  }
#pragma unroll
  for (int m = 32; m > 0; m >>= 1) s += __shfl_down(s, m);
  if (lane == 0) x2[row] = s;
}

// ---------------------------------------------------------------------------
// Gather initial centers + c2. One block per (r,l).
// ---------------------------------------------------------------------------
__global__ __launch_bounds__(256) void k_gather_init(const float* __restrict__ pts,
                                                     const int* __restrict__ init_idx,
                                                     float* __restrict__ centers,
                                                     float* __restrict__ c2) {
  const int l = blockIdx.x, r = blockIdx.y, t = threadIdx.x;
  const int idx = init_idx[r * L_ + l];
  const float4* src = (const float4*)(pts + ((size_t)r * N_ + idx) * D_);
  float4* dst = (float4*)(centers + ((size_t)r * L_ + l) * D_);
  float4 v = src[t];
  dst[t] = v;
  float s = v.x * v.x + v.y * v.y + v.z * v.z + v.w * v.w;
  __shared__ float red[4];
  const int lane = t & 63, wave = t >> 6;
#pragma unroll
  for (int m = 32; m > 0; m >>= 1) s += __shfl_down(s, m);
  if (lane == 0) red[wave] = s;
  __syncthreads();
  if (t == 0) c2[r * L_ + l] = red[0] + red[1] + red[2] + red[3];
}

// ---------------------------------------------------------------------------
// Assignment: labels[r][n] = argmin_l (x2[n] + c2[l]) - 2*dot(pts[n],centers[l])
// Block = 256 threads, tile = 128 points x 64 clusters, k-chunks of 64.
// When outp != nullptr (final iteration) the winning centroid row is copied
// straight to the output (gather fused, no separate k_final pass).
// ---------------------------------------------------------------------------
#define BN 128
#define BK 64
__global__ __launch_bounds__(256) void k_assign(const float* __restrict__ pts,
                                                const float* __restrict__ centers,
                                                const float* __restrict__ c2g,
                                                const float* __restrict__ x2g,
                                                int* __restrict__ labels,
                                                float* __restrict__ outp) {
  __shared__ __align__(16) float pT[BK][BN + 4];   // [kk][p], stride 132
  __shared__ __align__(16) float cT[BK][L_ + 4];   // [kk][l], stride 68
  const int t = threadIdx.x;
  const int r = blockIdx.y;
  const int n0 = blockIdx.x * BN;
  const int pg = t >> 3;        // 0..31
  const int cg = t & 7;         // 0..7
  const int p0 = pg * 4;
  const int l0 = cg * 8;

  const float* Pr = pts + ((size_t)r * N_ + n0) * D_;
  const float* Cr = centers + (size_t)r * L_ * D_;

  float acc[4][8];
#pragma unroll
  for (int i = 0; i < 4; ++i)
#pragma unroll
    for (int j = 0; j < 8; ++j) acc[i][j] = 0.f;

  for (int kb = 0; kb < D_; kb += BK) {
#pragma unroll
    for (int i = 0; i < 8; ++i) {
      int idx = i * 256 + t;
      int p = idx >> 4, kk = (idx & 15) * 4;
      float4 v = *(const float4*)(Pr + (size_t)p * D_ + kb + kk);
      pT[kk + 0][p] = v.x; pT[kk + 1][p] = v.y;
      pT[kk + 2][p] = v.z; pT[kk + 3][p] = v.w;
    }
#pragma unroll
    for (int i = 0; i < 4; ++i) {
      int idx = i * 256 + t;
      int l = idx >> 4, kk = (idx & 15) * 4;
      float4 v = *(const float4*)(Cr + (size_t)l * D_ + kb + kk);
      cT[kk + 0][l] = v.x; cT[kk + 1][l] = v.y;
      cT[kk + 2][l] = v.z; cT[kk + 3][l] = v.w;
    }
    __syncthreads();

    for (int kk = 0; kk < BK; ++kk) {
      float4 pv = *(const float4*)&pT[kk][p0];
      float4 ca = *(const float4*)&cT[kk][l0];
      float4 cb = *(const float4*)&cT[kk][l0 + 4];
      float pvs[4] = {pv.x, pv.y, pv.z, pv.w};
      float cvs[8] = {ca.x, ca.y, ca.z, ca.w, cb.x, cb.y, cb.z, cb.w};
#pragma unroll
      for (int i = 0; i < 4; ++i)
#pragma unroll
        for (int j = 0; j < 8; ++j)
          acc[i][j] = fmaf(pvs[i], cvs[j], acc[i][j]);
    }
    __syncthreads();
  }

  // epilogue: d2 and argmin (first-min tie-break, matching jnp.argmin)
  float c2v[8];
#pragma unroll
  for (int j = 0; j < 8; ++j) c2v[j] = c2g[r * L_ + l0 + j];

  int bis[4];
#pragma unroll
  for (int i = 0; i < 4; ++i) {
    const int n = n0 + p0 + i;
    const float x2i = x2g[r * N_ + n];
    float bv = 3.4e38f;
    int bi = 0;
#pragma unroll
    for (int j = 0; j < 8; ++j) {
      float d2 = (x2i + c2v[j]) - 2.0f * acc[i][j];
      if (d2 < bv) { bv = d2; bi = l0 + j; }
    }
#pragma unroll
    for (int m = 1; m < 8; m <<= 1) {
      float ov = __shfl_xor(bv, m);
      int oi = __shfl_xor(bi, m);
      if (ov < bv || (ov == bv && oi < bi)) { bv = ov; bi = oi; }
    }
    bis[i] = bi;
  }

  if (outp == nullptr) {
    if (cg == 0) {
#pragma unroll
      for (int i = 0; i < 4; ++i) labels[r * N_ + n0 + p0 + i] = bis[i];
    }
  } else {
    // fused gather: 8-lane group copies 4 winning centroid rows to out
#pragma unroll
    for (int i = 0; i < 4; ++i) {
      const int n = n0 + p0 + i;
      const float4* src = (const float4*)(centers + ((size_t)r * L_ + bis[i]) * D_);
      float4* dst = (float4*)(outp + ((size_t)r * N_ + n) * D_);
      for (int w = cg; w < D_ / 4; w += 8) dst[w] = src[w];
    }
  }
}

// ---------------------------------------------------------------------------
// Stable counting sort of labels. One block per r, 256 threads, each owning
// 16 consecutive points. Two-level exclusive scan -> deterministic, stable.
// Outputs: order[r][N] (point ids grouped by label, stable),
//          counts[r][L], starts[r][L].
// ---------------------------------------------------------------------------
__global__ __launch_bounds__(256) void k_sort(const int* __restrict__ labels,
                                              int* __restrict__ counts,
                                              int* __restrict__ starts,
                                              int* __restrict__ order) {
  __shared__ unsigned char lab[N_];
  __shared__ unsigned short cnt2[256 * 65];   // [t][l], stride 65 (u16)
  __shared__ int total[L_], base[L_];
  const int r = blockIdx.x, t = threadIdx.x;

  for (int i = t; i < N_; i += 256) lab[i] = (unsigned char)labels[r * N_ + i];
  for (int i = t; i < 256 * 65; i += 256) cnt2[i] = 0;
  __syncthreads();

  // pass 1: per-thread histogram (only thread t touches row t)
#pragma unroll 4
  for (int i = 0; i < 16; ++i) {
    int l = lab[t * 16 + i];
    cnt2[t * 65 + l]++;
  }
  __syncthreads();

  // per-label totals
  if (t < L_) {
    int s = 0;
    for (int tt = 0; tt < 256; ++tt) s += cnt2[tt * 65 + t];
    total[t] = s;
  }
  __syncthreads();
  if (t == 0) {
    int run = 0;
    for (int l = 0; l < L_; ++l) { base[l] = run; run += total[l]; }
  }
  __syncthreads();
  // per-(t,l) exclusive prefix over t, in place
  if (t < L_) {
    counts[r * L_ + t] = total[t];
    starts[r * L_ + t] = base[t];
    int run = base[t];
    for (int tt = 0; tt < 256; ++tt) {
      int v = cnt2[tt * 65 + t];
      cnt2[tt * 65 + t] = (unsigned short)run;
      run += v;
    }
  }
  __syncthreads();

  // scatter (stable: chunk-major order)
#pragma unroll 4
  for (int i = 0; i < 16; ++i) {
    int n = t * 16 + i;
    int l = lab[n];
    int pos = cnt2[t * 65 + l];
    cnt2[t * 65 + l] = (unsigned short)(pos + 1);
    order[r * N_ + pos] = n;
  }
}

// ---------------------------------------------------------------------------
// New centers: one block per (r,l). Gather-sum the cluster's points in stable
// sorted order (fixed 4-partial-accumulator scheme -> deterministic fp32),
// divide by count (IEEE), keep old center if empty; recompute c2.
// No LDS accumulator, 512 blocks -> 8 waves/CU.
// ---------------------------------------------------------------------------
__global__ __launch_bounds__(256) void k_centers(const float* __restrict__ pts,
                                                 const int* __restrict__ order,
                                                 const int* __restrict__ counts,
                                                 const int* __restrict__ starts,
                                                 float* __restrict__ centers,
                                                 float* __restrict__ c2) {
  const int l = blockIdx.x, r = blockIdx.y, t = threadIdx.x;
  const int cnt = counts[r * L_ + l];
  const int st  = starts[r * L_ + l];
  const int* ord = order + r * N_ + st;
  const float* base = pts + (size_t)r * N_ * D_;

  float4 a0 = {0,0,0,0}, a1 = a0, a2 = a0, a3 = a0;
  int j = 0;
  for (; j + 4 <= cnt; j += 4) {
    int i0 = ord[j], i1 = ord[j + 1], i2 = ord[j + 2], i3 = ord[j + 3];
    float4 v0 = ((const float4*)(base + (size_t)i0 * D_))[t];
    float4 v1 = ((const float4*)(base + (size_t)i1 * D_))[t];
    float4 v2 = ((const float4*)(base + (size_t)i2 * D_))[t];
    float4 v3 = ((const float4*)(base + (size_t)i3 * D_))[t];
    a0.x += v0.x; a0.y += v0.y; a0.z += v0.z; a0.w += v0.w;
    a1.x += v1.x; a1.y += v1.y; a1.z += v1.z; a1.w += v1.w;
    a2.x += v2.x; a2.y += v2.y; a2.z += v2.z; a2.w += v2.w;
    a3.x += v3.x; a3.y += v3.y; a3.z += v3.z; a3.w += v3.w;
  }
  for (; j < cnt; ++j) {
    int i0 = ord[j];
    float4 v0 = ((const float4*)(base + (size_t)i0 * D_))[t];
    a0.x += v0.x; a0.y += v0.y; a0.z += v0.z; a0.w += v0.w;
  }
  float4 s;
  s.x = (a0.x + a1.x) + (a2.x + a3.x);
  s.y = (a0.y + a1.y) + (a2.y + a3.y);
  s.z = (a0.z + a1.z) + (a2.z + a3.z);
  s.w = (a0.w + a1.w) + (a2.w + a3.w);

  float4* Crow = (float4*)(centers + ((size_t)r * L_ + l) * D_);
  float4 cn;
  if (cnt > 0) {
    const float denom = (float)cnt;
    cn.x = s.x / denom; cn.y = s.y / denom; cn.z = s.z / denom; cn.w = s.w / denom;
  } else {
    cn = Crow[t];
  }
  Crow[t] = cn;

  float ssq = cn.x * cn.x + cn.y * cn.y + cn.z * cn.z + cn.w * cn.w;
  __shared__ float red[4];
  const int lane = t & 63, wave = t >> 6;
#pragma unroll
  for (int m = 32; m > 0; m >>= 1) ssq += __shfl_down(ssq, m);
  if (lane == 0) red[wave] = ssq;
  __syncthreads();
  if (t == 0) c2[r * L_ + l] = red[0] + red[1] + red[2] + red[3];
}

// ---------------------------------------------------------------------------
extern "C" void kernel_launch(void* const* d_in, const int* in_sizes, int n_in,
                              void* d_out, int out_size, void* d_ws, size_t ws_size,
                              hipStream_t stream) {
  const float* x = (const float*)d_in[0];   // [512, 65536] == pts [8][4096][1024]
  float* out = (float*)d_out;               // [512, 65536] float32
  char* ws = (char*)d_ws;

  // workspace layout (bytes), total ~2.5 MB
  float* centers = (float*)(ws + 0);            // 2 MB
  float* c2      = (float*)(ws + 2097152);      // 2 KB
  float* x2      = (float*)(ws + 2099200);      // 128 KB
  int*   labels  = (int*)  (ws + 2230272);      // 128 KB
  int*   counts  = (int*)  (ws + 2361344);      // 2 KB
  int*   initidx = (int*)  (ws + 2363392);      // 2 KB
  int*   starts  = (int*)  (ws + 2365440);      // 2 KB
  int*   order   = (int*)  (ws + 2367488);      // 128 KB
  (void)in_sizes; (void)n_in; (void)out_size; (void)ws_size;

  k_rng<<<dim3(R_), 1024, 0, stream>>>(initidx);
  k_x2<<<dim3(ROWS / 4), 256, 0, stream>>>(x, x2);
  k_gather_init<<<dim3(L_, R_), 256, 0, stream>>>(x, initidx, centers, c2);

  for (int it = 0; it < ITERS; ++it) {
    k_assign<<<dim3(N_ / BN, R_), 256, 0, stream>>>(x, centers, c2, x2, labels, nullptr);
    k_sort<<<dim3(R_), 256, 0, stream>>>(labels, counts, starts, order);
    k_centers<<<dim3(L_, R_), 256, 0, stream>>>(x, order, counts, starts, centers, c2);
  }
  // final assignment with fused gather to output
  k_assign<<<dim3(N_ / BN, R_), 256, 0, stream>>>(x, centers, c2, x2, nullptr, out);
}

// Round 3
// 2193.407 us; speedup vs baseline: 1.1394x; 1.1394x over previous
//
#include <hip/hip_runtime.h>
#include <stdint.h>
#include <stddef.h>

// ---------------------------------------------------------------------------
// FedLite quantize: 8 independent KMeans (N=4096, d=1024, L=64, 10 iters)
// pts = x viewed as [R=8][N=4096][SUBD=1024] (reshape is layout-preserving).
// Init indices reproduce jax.random (threefry2x32, partitionable mode).
//
// Round-3 structure:
//   k_rng (1024 thr bitonic)                              ~30us
//   k_x2, k_gather_init                                   small
//   10x [ k_assign -> k_sort (stable counting sort)
//         -> k_csum (per-(r,l) partial sums, 4 pseg x 4 dch splits; kills
//            the round-2 load-imbalance tail: occupancy 1.5% -> >10%)
//         -> k_creduce (merge partials, divide, c2) ]
//   final k_assign writes d_out directly (gather fused)
// ---------------------------------------------------------------------------

static constexpr int R_    = 8;
static constexpr int N_    = 4096;
static constexpr int L_    = 64;
static constexpr int D_    = 1024;   // SUBD
static constexpr int ITERS = 10;
static constexpr int ROWS  = R_ * N_;   // 32768 total sub-vectors
static constexpr int PSEG  = 4;         // point-segments per cluster
static constexpr int DCH   = 4;         // dim-chunks of 256 floats

// ---------------------------------------------------------------------------
// Threefry2x32 (JAX flavor): 20 rounds, rotations {13,15,26,6}/{17,29,16,24}
// ---------------------------------------------------------------------------
__device__ __forceinline__ unsigned rotl32(unsigned x, int r) {
  return (x << r) | (x >> (32 - r));
}

__device__ __forceinline__ void tf2x32(unsigned k0, unsigned k1,
                                       unsigned c0, unsigned c1,
                                       unsigned &o0, unsigned &o1) {
  unsigned ks2 = k0 ^ k1 ^ 0x1BD11BDAu;
  unsigned x0 = c0 + k0, x1 = c1 + k1;
#define TF_R4(a,b,c,d) { x0 += x1; x1 = rotl32(x1,a); x1 ^= x0; \
                         x0 += x1; x1 = rotl32(x1,b); x1 ^= x0; \
                         x0 += x1; x1 = rotl32(x1,c); x1 ^= x0; \
                         x0 += x1; x1 = rotl32(x1,d); x1 ^= x0; }
  TF_R4(13,15,26,6);  x0 += k1;  x1 += ks2 + 1u;
  TF_R4(17,29,16,24); x0 += ks2; x1 += k0  + 2u;
  TF_R4(13,15,26,6);  x0 += k0;  x1 += k1  + 3u;
  TF_R4(17,29,16,24); x0 += k1;  x1 += ks2 + 4u;
  TF_R4(13,15,26,6);  x0 += ks2; x1 += k0  + 5u;
#undef TF_R4
  o0 = x0; o1 = x1;
}

// split(key) -> (new_key, subkey), partitionable mode (verified round 1)
__device__ __forceinline__ void jax_split2(unsigned k0, unsigned k1,
                                           unsigned &nk0, unsigned &nk1,
                                           unsigned &sk0, unsigned &sk1) {
  tf2x32(k0, k1, 0u, 0u, nk0, nk1);
  tf2x32(k0, k1, 0u, 1u, sk0, sk1);
}

// ---------------------------------------------------------------------------
// RNG kernel: one block (1024 thr) per KMeans problem r.
// init_idx[r][0..63] = jax.random.permutation(key_r, 4096)[:64] via 2 rounds
// of stable sort by threefry keys (bitonic on (key32, slot|value)).
// ---------------------------------------------------------------------------
__global__ __launch_bounds__(1024) void k_rng(int* __restrict__ init_idx) {
  __shared__ unsigned skey[N_];
  __shared__ unsigned spay[N_];
  __shared__ unsigned short perm[N_];
  const int r = blockIdx.x;
  const int t = threadIdx.x;

  unsigned k0, k1;
  tf2x32(0u, 42u, 0u, (unsigned)r, k0, k1);   // key_r = split(key(42), 8)[r]

  for (int i = t; i < N_; i += 1024) perm[i] = (unsigned short)i;
  __syncthreads();

  for (int round = 0; round < 2; ++round) {
    unsigned nk0, nk1, s0, s1;
    jax_split2(k0, k1, nk0, nk1, s0, s1);
    for (int j = t; j < N_; j += 1024) {
      unsigned o0, o1;
      tf2x32(s0, s1, 0u, (unsigned)j, o0, o1);
      skey[j] = o0 ^ o1;                                   // random_bits(32)
      spay[j] = ((unsigned)j << 12) | (unsigned)perm[j];   // slot|value
    }
    __syncthreads();
    for (int k = 2; k <= N_; k <<= 1) {
      for (int j2 = k >> 1; j2 >= 1; j2 >>= 1) {
        for (int q = t; q < N_ / 2; q += 1024) {
          int low = q & (j2 - 1);
          int i0 = ((q ^ low) << 1) | low;
          int i1 = i0 | j2;
          bool up = ((i0 & k) == 0);
          unsigned ka = skey[i0], kb = skey[i1];
          unsigned pa = spay[i0], pb = spay[i1];
          bool agtb = (ka > kb) || (ka == kb && pa > pb);
          if (agtb == up) {
            skey[i0] = kb; skey[i1] = ka;
            spay[i0] = pb; spay[i1] = pa;
          }
        }
        __syncthreads();
      }
    }
    for (int j = t; j < N_; j += 1024) perm[j] = (unsigned short)(spay[j] & 0xFFFu);
    __syncthreads();
    k0 = nk0; k1 = nk1;
  }
  if (t < L_) init_idx[r * L_ + t] = (int)perm[t];
}

// ---------------------------------------------------------------------------
// x2[row] = sum of squares of pts row (computed once). 4 rows per block.
// ---------------------------------------------------------------------------
__global__ __launch_bounds__(256) void k_x2(const float* __restrict__ pts,
                                            float* __restrict__ x2) {
  const int t = threadIdx.x;
  const int lane = t & 63;
  const int row = blockIdx.x * 4 + (t >> 6);
  const float4* P = (const float4*)(pts + (size_t)row * D_);
  float s = 0.f;
#pragma unroll
  for (int i = 0; i < 4; ++i) {
    float4 v = P[lane + 64 * i];
    s += v.x * v.x + v.y * v.y + v.z * v.z + v.w * v.w;
  }
#pragma unroll
  for (int m = 32; m > 0; m >>= 1) s += __shfl_down(s, m);
  if (lane == 0) x2[row] = s;
}

// ---------------------------------------------------------------------------
// Gather initial centers + c2. One block per (r,l).
// ---------------------------------------------------------------------------
__global__ __launch_bounds__(256) void k_gather_init(const float* __restrict__ pts,
                                                     const int* __restrict__ init_idx,
                                                     float* __restrict__ centers,
                                                     float* __restrict__ c2) {
  const int l = blockIdx.x, r = blockIdx.y, t = threadIdx.x;
  const int idx = init_idx[r * L_ + l];
  const float4* src = (const float4*)(pts + ((size_t)r * N_ + idx) * D_);
  float4* dst = (float4*)(centers + ((size_t)r * L_ + l) * D_);
  float4 v = src[t];
  dst[t] = v;
  float s = v.x * v.x + v.y * v.y + v.z * v.z + v.w * v.w;
  __shared__ float red[4];
  const int lane = t & 63, wave = t >> 6;
#pragma unroll
  for (int m = 32; m > 0; m >>= 1) s += __shfl_down(s, m);
  if (lane == 0) red[wave] = s;
  __syncthreads();
  if (t == 0) c2[r * L_ + l] = red[0] + red[1] + red[2] + red[3];
}

// ---------------------------------------------------------------------------
// Assignment: labels[r][n] = argmin_l (x2[n] + c2[l]) - 2*dot(pts[n],centers[l])
// Block = 256 threads, tile = 128 points x 64 clusters, k-chunks of 64.
// When outp != nullptr (final iteration) the winning centroid row is copied
// straight to the output (gather fused).  UNCHANGED from round 2 (79us est;
// will be optimized next round with its own counters).
// ---------------------------------------------------------------------------
#define BN 128
#define BK 64
__global__ __launch_bounds__(256) void k_assign(const float* __restrict__ pts,
                                                const float* __restrict__ centers,
                                                const float* __restrict__ c2g,
                                                const float* __restrict__ x2g,
                                                int* __restrict__ labels,
                                                float* __restrict__ outp) {
  __shared__ __align__(16) float pT[BK][BN + 4];   // [kk][p], stride 132
  __shared__ __align__(16) float cT[BK][L_ + 4];   // [kk][l], stride 68
  const int t = threadIdx.x;
  const int r = blockIdx.y;
  const int n0 = blockIdx.x * BN;
  const int pg = t >> 3;        // 0..31
  const int cg = t & 7;         // 0..7
  const int p0 = pg * 4;
  const int l0 = cg * 8;

  const float* Pr = pts + ((size_t)r * N_ + n0) * D_;
  const float* Cr = centers + (size_t)r * L_ * D_;

  float acc[4][8];
#pragma unroll
  for (int i = 0; i < 4; ++i)
#pragma unroll
    for (int j = 0; j < 8; ++j) acc[i][j] = 0.f;

  for (int kb = 0; kb < D_; kb += BK) {
#pragma unroll
    for (int i = 0; i < 8; ++i) {
      int idx = i * 256 + t;
      int p = idx >> 4, kk = (idx & 15) * 4;
      float4 v = *(const float4*)(Pr + (size_t)p * D_ + kb + kk);
      pT[kk + 0][p] = v.x; pT[kk + 1][p] = v.y;
      pT[kk + 2][p] = v.z; pT[kk + 3][p] = v.w;
    }
#pragma unroll
    for (int i = 0; i < 4; ++i) {
      int idx = i * 256 + t;
      int l = idx >> 4, kk = (idx & 15) * 4;
      float4 v = *(const float4*)(Cr + (size_t)l * D_ + kb + kk);
      cT[kk + 0][l] = v.x; cT[kk + 1][l] = v.y;
      cT[kk + 2][l] = v.z; cT[kk + 3][l] = v.w;
    }
    __syncthreads();

    for (int kk = 0; kk < BK; ++kk) {
      float4 pv = *(const float4*)&pT[kk][p0];
      float4 ca = *(const float4*)&cT[kk][l0];
      float4 cb = *(const float4*)&cT[kk][l0 + 4];
      float pvs[4] = {pv.x, pv.y, pv.z, pv.w};
      float cvs[8] = {ca.x, ca.y, ca.z, ca.w, cb.x, cb.y, cb.z, cb.w};
#pragma unroll
      for (int i = 0; i < 4; ++i)
#pragma unroll
        for (int j = 0; j < 8; ++j)
          acc[i][j] = fmaf(pvs[i], cvs[j], acc[i][j]);
    }
    __syncthreads();
  }

  // epilogue: d2 and argmin (first-min tie-break, matching jnp.argmin)
  float c2v[8];
#pragma unroll
  for (int j = 0; j < 8; ++j) c2v[j] = c2g[r * L_ + l0 + j];

  int bis[4];
#pragma unroll
  for (int i = 0; i < 4; ++i) {
    const int n = n0 + p0 + i;
    const float x2i = x2g[r * N_ + n];
    float bv = 3.4e38f;
    int bi = 0;
#pragma unroll
    for (int j = 0; j < 8; ++j) {
      float d2 = (x2i + c2v[j]) - 2.0f * acc[i][j];
      if (d2 < bv) { bv = d2; bi = l0 + j; }
    }
#pragma unroll
    for (int m = 1; m < 8; m <<= 1) {
      float ov = __shfl_xor(bv, m);
      int oi = __shfl_xor(bi, m);
      if (ov < bv || (ov == bv && oi < bi)) { bv = ov; bi = oi; }
    }
    bis[i] = bi;
  }

  if (outp == nullptr) {
    if (cg == 0) {
#pragma unroll
      for (int i = 0; i < 4; ++i) labels[r * N_ + n0 + p0 + i] = bis[i];
    }
  } else {
    // fused gather: 8-lane group copies 4 winning centroid rows to out
#pragma unroll
    for (int i = 0; i < 4; ++i) {
      const int n = n0 + p0 + i;
      const float4* src = (const float4*)(centers + ((size_t)r * L_ + bis[i]) * D_);
      float4* dst = (float4*)(outp + ((size_t)r * N_ + n) * D_);
      for (int w = cg; w < D_ / 4; w += 8) dst[w] = src[w];
    }
  }
}

// ---------------------------------------------------------------------------
// Stable counting sort of labels. One block per r, 256 threads, each owning
// 16 consecutive points. Two-level exclusive scan -> deterministic, stable.
// ---------------------------------------------------------------------------
__global__ __launch_bounds__(256) void k_sort(const int* __restrict__ labels,
                                              int* __restrict__ counts,
                                              int* __restrict__ starts,
                                              int* __restrict__ order) {
  __shared__ unsigned char lab[N_];
  __shared__ unsigned short cnt2[256 * 65];   // [t][l], stride 65 (u16)
  __shared__ int total[L_], base[L_];
  const int r = blockIdx.x, t = threadIdx.x;

  for (int i = t; i < N_; i += 256) lab[i] = (unsigned char)labels[r * N_ + i];
  for (int i = t; i < 256 * 65; i += 256) cnt2[i] = 0;
  __syncthreads();

#pragma unroll 4
  for (int i = 0; i < 16; ++i) {
    int l = lab[t * 16 + i];
    cnt2[t * 65 + l]++;
  }
  __syncthreads();

  if (t < L_) {
    int s = 0;
    for (int tt = 0; tt < 256; ++tt) s += cnt2[tt * 65 + t];
    total[t] = s;
  }
  __syncthreads();
  if (t == 0) {
    int run = 0;
    for (int l = 0; l < L_; ++l) { base[l] = run; run += total[l]; }
  }
  __syncthreads();
  if (t < L_) {
    counts[r * L_ + t] = total[t];
    starts[r * L_ + t] = base[t];
    int run = base[t];
    for (int tt = 0; tt < 256; ++tt) {
      int v = cnt2[tt * 65 + t];
      cnt2[tt * 65 + t] = (unsigned short)run;
      run += v;
    }
  }
  __syncthreads();

#pragma unroll 4
  for (int i = 0; i < 16; ++i) {
    int n = t * 16 + i;
    int l = lab[n];
    int pos = cnt2[t * 65 + l];
    cnt2[t * 65 + l] = (unsigned short)(pos + 1);
    order[r * N_ + pos] = n;
  }
}

// ---------------------------------------------------------------------------
// Partial cluster sums. Grid (L, R, PSEG*DCH), block = 1 wave (64 thr).
// Block (l, r, pseg, dch) sums points ord[st + lo..hi) over dims
// [dch*256, dch*256+256) into psums[pseg][r][l][dch*256..].  Every chunk is
// written by exactly one block (no pre-zero needed), fixed order -> fully
// deterministic.  8192 blocks kills the round-2 tail (biggest cluster split
// 4x over points; 32 waves/CU of co-runners hide HBM latency).
// ---------------------------------------------------------------------------
__global__ __launch_bounds__(64) void k_csum(const float* __restrict__ pts,
                                             const int* __restrict__ order,
                                             const int* __restrict__ counts,
                                             const int* __restrict__ starts,
                                             float* __restrict__ psums) {
  const int l = blockIdx.x, r = blockIdx.y;
  const int pseg = blockIdx.z & (PSEG - 1);
  const int dch  = blockIdx.z >> 2;
  const int t = threadIdx.x;           // 0..63
  const int cnt = counts[r * L_ + l];
  const int st  = starts[r * L_ + l];
  const int lo = (cnt * pseg) / PSEG;
  const int hi = (cnt * (pseg + 1)) / PSEG;
  const int* ord = order + r * N_ + st;
  const float* base = pts + (size_t)r * N_ * D_ + dch * 256;

  float4 a0 = {0,0,0,0}, a1 = a0, a2 = a0, a3 = a0;
  int j = lo;
  for (; j + 4 <= hi; j += 4) {
    int i0 = ord[j], i1 = ord[j + 1], i2 = ord[j + 2], i3 = ord[j + 3];
    float4 v0 = ((const float4*)(base + (size_t)i0 * D_))[t];
    float4 v1 = ((const float4*)(base + (size_t)i1 * D_))[t];
    float4 v2 = ((const float4*)(base + (size_t)i2 * D_))[t];
    float4 v3 = ((const float4*)(base + (size_t)i3 * D_))[t];
    a0.x += v0.x; a0.y += v0.y; a0.z += v0.z; a0.w += v0.w;
    a1.x += v1.x; a1.y += v1.y; a1.z += v1.z; a1.w += v1.w;
    a2.x += v2.x; a2.y += v2.y; a2.z += v2.z; a2.w += v2.w;
    a3.x += v3.x; a3.y += v3.y; a3.z += v3.z; a3.w += v3.w;
  }
  for (; j < hi; ++j) {
    float4 v0 = ((const float4*)(base + (size_t)ord[j] * D_))[t];
    a0.x += v0.x; a0.y += v0.y; a0.z += v0.z; a0.w += v0.w;
  }
  float4 s;
  s.x = (a0.x + a1.x) + (a2.x + a3.x);
  s.y = (a0.y + a1.y) + (a2.y + a3.y);
  s.z = (a0.z + a1.z) + (a2.z + a3.z);
  s.w = (a0.w + a1.w) + (a2.w + a3.w);

  float4* dst = (float4*)(psums + (((size_t)pseg * R_ + r) * L_ + l) * D_ + dch * 256);
  dst[t] = s;
}

// ---------------------------------------------------------------------------
// Merge partials -> new centers (+ c2). One block per (r,l).
// ---------------------------------------------------------------------------
__global__ __launch_bounds__(256) void k_creduce(const float* __restrict__ psums,
                                                 const int* __restrict__ counts,
                                                 float* __restrict__ centers,
                                                 float* __restrict__ c2) {
  const int l = blockIdx.x, r = blockIdx.y, t = threadIdx.x;
  const int cnt = counts[r * L_ + l];

  float4 s = {0.f, 0.f, 0.f, 0.f};
#pragma unroll
  for (int p = 0; p < PSEG; ++p) {
    const float4 v = *(const float4*)(psums + (((size_t)p * R_ + r) * L_ + l) * D_ + t * 4);
    s.x += v.x; s.y += v.y; s.z += v.z; s.w += v.w;
  }
  float4* Crow = (float4*)(centers + ((size_t)r * L_ + l) * D_);
  float4 cn;
  if (cnt > 0) {
    const float denom = (float)cnt;
    cn.x = s.x / denom; cn.y = s.y / denom; cn.z = s.z / denom; cn.w = s.w / denom;
  } else {
    cn = Crow[t];
  }
  Crow[t] = cn;

  float ssq = cn.x * cn.x + cn.y * cn.y + cn.z * cn.z + cn.w * cn.w;
  __shared__ float red[4];
  const int lane = t & 63, wave = t >> 6;
#pragma unroll
  for (int m = 32; m > 0; m >>= 1) ssq += __shfl_down(ssq, m);
  if (lane == 0) red[wave] = ssq;
  __syncthreads();
  if (t == 0) c2[r * L_ + l] = red[0] + red[1] + red[2] + red[3];
}

// ---------------------------------------------------------------------------
extern "C" void kernel_launch(void* const* d_in, const int* in_sizes, int n_in,
                              void* d_out, int out_size, void* d_ws, size_t ws_size,
                              hipStream_t stream) {
  const float* x = (const float*)d_in[0];   // [512, 65536] == pts [8][4096][1024]
  float* out = (float*)d_out;               // [512, 65536] float32
  char* ws = (char*)d_ws;

  // workspace layout (bytes), total ~10.9 MB
  float* centers = (float*)(ws + 0);            // 2 MB
  float* c2      = (float*)(ws + 2097152);      // 2 KB
  float* x2      = (float*)(ws + 2099200);      // 128 KB
  int*   labels  = (int*)  (ws + 2230272);      // 128 KB
  int*   counts  = (int*)  (ws + 2361344);      // 2 KB
  int*   initidx = (int*)  (ws + 2363392);      // 2 KB
  int*   starts  = (int*)  (ws + 2365440);      // 2 KB
  int*   order   = (int*)  (ws + 2367488);      // 128 KB
  float* psums   = (float*)(ws + 2498560);      // 8 MB  [PSEG][R][L][D]
  (void)in_sizes; (void)n_in; (void)out_size; (void)ws_size;

  k_rng<<<dim3(R_), 1024, 0, stream>>>(initidx);
  k_x2<<<dim3(ROWS / 4), 256, 0, stream>>>(x, x2);
  k_gather_init<<<dim3(L_, R_), 256, 0, stream>>>(x, initidx, centers, c2);

  for (int it = 0; it < ITERS; ++it) {
    k_assign<<<dim3(N_ / BN, R_), 256, 0, stream>>>(x, centers, c2, x2, labels, nullptr);
    k_sort<<<dim3(R_), 256, 0, stream>>>(labels, counts, starts, order);
    k_csum<<<dim3(L_, R_, PSEG * DCH), 64, 0, stream>>>(x, order, counts, starts, psums);
    k_creduce<<<dim3(L_, R_), 256, 0, stream>>>(psums, counts, centers, c2);
  }
  // final assignment with fused gather to output
  k_assign<<<dim3(N_ / BN, R_), 256, 0, stream>>>(x, centers, c2, x2, nullptr, out);
}